// Round 11
// baseline (63.805 us; speedup 1.0000x reference)
//
#include <hip/hip_runtime.h>
#include <hip/hip_bf16.h>
#include <math.h>

typedef __attribute__((ext_vector_type(8))) short short8;
typedef __attribute__((ext_vector_type(16))) float f32x16;

union U {
    unsigned u[4];
    short8 s;
};

struct FragH {         // one component (re or im) bf16 operand, 2 k-tiles
    U f[2];
};

static __device__ __forceinline__ unsigned short f2bf(float x) {
    __bf16 b = (__bf16)x;                       // RNE, native v_cvt on gfx950
    return __builtin_bit_cast(unsigned short, b);
}
static __device__ __forceinline__ unsigned packbf(float a, float b) {
    return (unsigned)f2bf(a) | ((unsigned)f2bf(b) << 16);
}

#define MFMA(A, B, C) __builtin_amdgcn_mfma_f32_32x32x16_bf16((A).s, (B).s, (C), 0, 0, 0)

// ---------------------------------------------------------------------------
// Workspace layout (bytes):
//   0      : tabs  float2[4096]  (F, Finv, -, conj-twiddle -- for kf_kernel)
//   32768  : T1    float2[1024]  (pure twiddle exp(-2pi i rc/N), C/D order)
//   49152  : Ftab  uint4 [384]   (bf16 fragment tables: cos, -sin, +sin)
//   65536  : kf_cd float2[128*1024] (filter spectrum / 1024, C/D order)
// ---------------------------------------------------------------------------

__global__ __launch_bounds__(256) void fft_tables(float2* tabs, float2* T1, uint4* Ftab) {
    int gid = blockIdx.x * 256 + threadIdx.x;       // grid 16*256 = 4096
    if (gid < 1024) {
        int i = gid;
        int r = i >> 5, c = i & 31;
        float s32, c32;
        sincospif((float)((r * c) & 31) / 16.0f, &s32, &c32);
        s32 = -s32;                                  // exp(-2pi i rc/32)
        tabs[i]        = make_float2(c32,  s32);     // F
        tabs[1024 + i] = make_float2(c32, -s32);     // Finv
        float sN, cN;
        sincospif((float)(r * c) / 512.0f, &sN, &cN);
        sN = -sN;                                    // exp(-2pi i rc/1024)
        tabs[2048 + i] = make_float2(cN / 1024.0f, sN / 1024.0f);
        tabs[3072 + i] = make_float2(cN, -sN);
        // T1[m][l] = twiddle[l&31][row(m,l)] (symmetric), no 1/N (in kf_cd)
        int m = i >> 6, l = i & 63;
        int row = (m & 3) + 8 * (m >> 2) + 4 * (l >> 5);
        int prod = (l & 31) * row;
        float st, ct;
        sincospif((float)prod / 512.0f, &st, &ct);
        T1[i] = make_float2(ct, -st);
    }
    if (gid < 1536) {
        // Ftab: 3 comps x 2 ktiles x 64 lanes x 4 vgprs, packed bf16 pairs.
        // comp 0: cos ; 1: -sin (=im F) ; 2: +sin (=im Finv)
        int c = gid >> 9;
        int rem = gid & 511;
        int t = rem >> 8;
        int sub = rem & 255;
        int l = sub >> 2;
        int v = sub & 3;
        int k0 = 16 * t + 8 * (l >> 5) + 2 * v;
        int j = l & 31;
        unsigned short sh[2];
        for (int q = 0; q < 2; q++) {
            int k = k0 + q;
            float sa, ca;
            sincospif((float)((k * j) & 31) / 16.0f, &sa, &ca);
            float base = (c == 0) ? ca : ((c == 1) ? -sa : sa);
            sh[q] = f2bf(base);
        }
        ((unsigned*)Ftab)[((c * 2 + t) * 64 + l) * 4 + v] =
            (unsigned)sh[0] | ((unsigned)sh[1] << 16);
    }
}

// Filter spectrum kfT[h][k1][k2] = FFT_1024(k[h])[32*k2+k1], written permuted
// AND scaled by 1/1024: kf_cd[h][m][l] = kfT[h][l&31][row(m,l)] / 1024
__global__ __launch_bounds__(256) void kf_kernel(const float* __restrict__ kin,
                                                 const float2* __restrict__ tabs,
                                                 float2* __restrict__ kf_cd) {
    __shared__ float  sx[1024];
    __shared__ float2 sA[1024];
    const int h = blockIdx.x, t = threadIdx.x;
    for (int i = t; i < 1024; i += 256) sx[i] = kin[h * 1024 + i];
    __syncthreads();
    const int r = t >> 3, c0 = (t & 7) << 2;

    float2 acc[4];
    for (int j = 0; j < 4; j++) acc[j] = make_float2(0.f, 0.f);
    #pragma unroll 8
    for (int n1 = 0; n1 < 32; n1++) {
        float2 f = tabs[r * 32 + n1];
        for (int j = 0; j < 4; j++) {
            float xv = sx[n1 * 32 + c0 + j];
            acc[j].x += f.x * xv;
            acc[j].y += f.y * xv;
        }
    }
    for (int j = 0; j < 4; j++) {
        float2 w = tabs[3072 + r * 32 + c0 + j];   // conj -> exp(-2pi i rc/N)
        sA[r * 32 + c0 + j] = make_float2(acc[j].x * w.x + acc[j].y * w.y,
                                          acc[j].y * w.x - acc[j].x * w.y);
    }
    __syncthreads();
    for (int j = 0; j < 4; j++) acc[j] = make_float2(0.f, 0.f);
    #pragma unroll 8
    for (int n2 = 0; n2 < 32; n2++) {
        float2 a = sA[r * 32 + n2];
        for (int j = 0; j < 4; j++) {
            float2 f = tabs[n2 * 32 + c0 + j];
            acc[j].x += a.x * f.x - a.y * f.y;
            acc[j].y += a.x * f.y + a.y * f.x;
        }
    }
    for (int j = 0; j < 4; j++) {
        int k2 = c0 + j;
        int m = (k2 & 3) | ((k2 >> 3) << 2);
        int hl = (k2 >> 2) & 1;
        kf_cd[h * 1024 + m * 64 + hl * 32 + r] =
            make_float2(acc[j].x * (1.0f / 1024.0f), acc[j].y * (1.0f / 1024.0f));
    }
}

// C/D accumulator -> bf16 A/B fragment via v_permlane32_swap_b32:
// swap(a,b): a.hi <-> b.lo => a = [a.lo;b.lo], b = [a.hi;b.hi]
static __device__ __forceinline__ void convertP(const f32x16& acc, FragH& out) {
    #pragma unroll
    for (int t = 0; t < 2; t++) {
        unsigned a0 = packbf(acc[8 * t + 0], acc[8 * t + 1]);
        unsigned a1 = packbf(acc[8 * t + 2], acc[8 * t + 3]);
        unsigned b0 = packbf(acc[8 * t + 4], acc[8 * t + 5]);
        unsigned b1 = packbf(acc[8 * t + 6], acc[8 * t + 7]);
        asm("v_permlane32_swap_b32 %0, %1" : "+v"(a0), "+v"(b0));
        asm("v_permlane32_swap_b32 %0, %1" : "+v"(a1), "+v"(b1));
        out.f[t].u[0] = a0;
        out.f[t].u[1] = a1;
        out.f[t].u[2] = b0;
        out.f[t].u[3] = b1;
    }
}

// One packed-pair complex four-step (R8 algebra), tables from LDS.
static __device__ __forceinline__ void compute_pair(
        const U Xr[2], const U Xi[2], const U F[3][2],
        const float2* __restrict__ sT1, const float2* __restrict__ sKF,
        float* __restrict__ opr, float* __restrict__ opi,
        int lane, int hl, int col) {
    const f32x16 Z16 = {0,0,0,0,0,0,0,0,0,0,0,0,0,0,0,0};

    // Stage 1: Y^T = Z^T @ F   (Yr = Xr@C + Xi@sin ; Yi = Xr@S + Xi@C)
    f32x16 aR = Z16, aI = Z16;
    #pragma unroll
    for (int t = 0; t < 2; t++) {
        aR = MFMA(Xr[t], F[0][t], aR); aR = MFMA(Xi[t], F[2][t], aR);
        aI = MFMA(Xr[t], F[1][t], aI); aI = MFMA(Xi[t], F[0][t], aI);
    }
    #pragma unroll
    for (int m = 0; m < 16; m++) {                 // twiddle (1/N in kf)
        float2 tm = sT1[m * 64 + lane];
        float rr = aR[m] * tm.x - aI[m] * tm.y;
        float ii = aR[m] * tm.y + aI[m] * tm.x;
        aR[m] = rr; aI[m] = ii;
    }
    FragH Yr, Yi;
    convertP(aR, Yr);
    convertP(aI, Yi);

    // Stage 3: Z^T = F @ Y^T  (Zr = C@Yr + sin@Yi ; Zi = C@Yi + S@Yr)
    f32x16 bR = Z16, bI = Z16;
    #pragma unroll
    for (int t = 0; t < 2; t++) {
        bR = MFMA(F[0][t], Yr.f[t], bR); bR = MFMA(F[2][t], Yi.f[t], bR);
        bI = MFMA(F[0][t], Yi.f[t], bI); bI = MFMA(F[1][t], Yr.f[t], bI);
    }
    #pragma unroll
    for (int m = 0; m < 16; m++) {                 // filter (has 1/N)
        float2 kv = sKF[m * 64 + lane];
        float rr = bR[m] * kv.x - bI[m] * kv.y;
        float ii = bR[m] * kv.y + bI[m] * kv.x;
        bR[m] = rr; bI[m] = ii;
    }
    FragH Zr, Zi;
    convertP(bR, Zr);
    convertP(bI, Zi);

    // Stage 5: W = Z @ Finv  (Wr = Zr@C + Zi@S ; Wi = Zr@sin + Zi@C)
    aR = Z16; aI = Z16;
    #pragma unroll
    for (int t = 0; t < 2; t++) {
        aR = MFMA(Zr.f[t], F[0][t], aR); aR = MFMA(Zi.f[t], F[1][t], aR);
        aI = MFMA(Zr.f[t], F[2][t], aI); aI = MFMA(Zi.f[t], F[0][t], aI);
    }
    #pragma unroll
    for (int m = 0; m < 16; m++) {                 // conj twiddle (no scale)
        float2 tm = sT1[m * 64 + lane];
        float rr = aR[m] * tm.x + aI[m] * tm.y;
        float ii = aI[m] * tm.x - aR[m] * tm.y;
        aR[m] = rr; aI[m] = ii;
    }
    FragH Wr, Wi;
    convertP(aR, Wr);
    convertP(aI, Wi);

    // Stage 7: y = Finv @ W  (yR = C@Wr + S@Wi ; yI = C@Wi + sin@Wr)
    f32x16 yR = Z16, yI = Z16;
    #pragma unroll
    for (int t = 0; t < 2; t++) {
        yR = MFMA(F[0][t], Wr.f[t], yR); yR = MFMA(F[1][t], Wi.f[t], yR);
        yI = MFMA(F[0][t], Wi.f[t], yI); yI = MFMA(F[2][t], Wr.f[t], yI);
    }
    #pragma unroll
    for (int m = 0; m < 16; m++) {
        int off = ((m & 3) + 8 * (m >> 2) + 4 * hl) * 32 + col;
        opr[off] = yR[m];
        opi[off] = yI[m];
    }
}

// R11: R8 structure + software pipeline:
//  - both units of a block share h -> sT1/sKF staged once, one barrier;
//  - unit1's 32 input loads issued BEFORE unit0's compute (HBM latency hides
//    under ~2500cyc of compute); t1 back in LDS so the pipeline is reg-neutral.
__global__ __launch_bounds__(256, 3) void conv_mfma(const float* __restrict__ u,
                                                    const float2* __restrict__ T1,
                                                    const uint4* __restrict__ Ftab,
                                                    const float2* __restrict__ KF,
                                                    float* __restrict__ out) {
    __shared__ float2 sT1[1024];    // 8 KB
    __shared__ float2 sKF[1024];    // 8 KB

    const int tid = threadIdx.x;
    const int lane = tid & 63;
    const int wave = tid >> 6;
    const int col = lane & 31;
    const int hl = lane >> 5;
    const size_t tile_stride = (size_t)128 * 1024;

    const int h = blockIdx.x >> 3;                       // 8 blocks per h
    const int off0 = (blockIdx.x & 7) * 8 + wave * 2;    // pair idx in h, unit 0
    const int b0_0 = off0 * 2;                           // unit 0: b0_0, b0_0+1
    const int b0_1 = b0_0 + 2;                           // unit 1: b0_1, b0_1+1

    // ---- Issue unit 0 input loads first (overlap with LDS staging below).
    const float* upr0 = u + ((size_t)(b0_0 * 128 + h) << 10);
    const float* upi0 = upr0 + tile_stride;
    float xr0[2][8], xi0[2][8];
    #pragma unroll
    for (int t = 0; t < 2; t++)
        #pragma unroll
        for (int e = 0; e < 8; e++) {
            int off = (16 * t + 8 * hl + e) * 32 + col;
            xr0[t][e] = upr0[off];
            xi0[t][e] = upi0[off];
        }

    // ---- Stage shared tables (once per block; both units share h).
    for (int i = tid; i < 1024; i += 256) {
        sT1[i] = T1[i];
        sKF[i] = KF[h * 1024 + i];
    }

    // ---- F fragment tables: F[0]=cos, F[1]=-sin, F[2]=+sin
    U F[3][2];
    #pragma unroll
    for (int c = 0; c < 3; c++)
        #pragma unroll
        for (int t = 0; t < 2; t++) {
            uint4 raw = Ftab[(c * 2 + t) * 64 + lane];
            F[c][t].u[0] = raw.x; F[c][t].u[1] = raw.y;
            F[c][t].u[2] = raw.z; F[c][t].u[3] = raw.w;
        }
    __syncthreads();

    // ---- Pack unit 0.
    U Xr[2], Xi[2];
    #pragma unroll
    for (int t = 0; t < 2; t++)
        #pragma unroll
        for (int v = 0; v < 4; v++) {
            Xr[t].u[v] = packbf(xr0[t][2 * v], xr0[t][2 * v + 1]);
            Xi[t].u[v] = packbf(xi0[t][2 * v], xi0[t][2 * v + 1]);
        }

    // ---- Prefetch unit 1 inputs (in flight during unit 0 compute).
    const float* upr1 = u + ((size_t)(b0_1 * 128 + h) << 10);
    const float* upi1 = upr1 + tile_stride;
    float xr1[2][8], xi1[2][8];
    #pragma unroll
    for (int t = 0; t < 2; t++)
        #pragma unroll
        for (int e = 0; e < 8; e++) {
            int off = (16 * t + 8 * hl + e) * 32 + col;
            xr1[t][e] = upr1[off];
            xi1[t][e] = upi1[off];
        }

    // ---- Unit 0 compute + store.
    {
        float* opr = out + ((size_t)(b0_0 * 128 + h) << 10);
        float* opi = opr + tile_stride;
        compute_pair(Xr, Xi, F, sT1, sKF, opr, opi, lane, hl, col);
    }

    // ---- Pack unit 1, compute + store.
    #pragma unroll
    for (int t = 0; t < 2; t++)
        #pragma unroll
        for (int v = 0; v < 4; v++) {
            Xr[t].u[v] = packbf(xr1[t][2 * v], xr1[t][2 * v + 1]);
            Xi[t].u[v] = packbf(xi1[t][2 * v], xi1[t][2 * v + 1]);
        }
    {
        float* opr = out + ((size_t)(b0_1 * 128 + h) << 10);
        float* opi = opr + tile_stride;
        compute_pair(Xr, Xi, F, sT1, sKF, opr, opi, lane, hl, col);
    }
}

extern "C" void kernel_launch(void* const* d_in, const int* in_sizes, int n_in,
                              void* d_out, int out_size, void* d_ws, size_t ws_size,
                              hipStream_t stream) {
    const float* u = (const float*)d_in[0];   // (B=128, H=128, N=1024)
    const float* k = (const float*)d_in[1];   // (H=128, N=1024)
    float* out = (float*)d_out;               // (B, H, N) float32

    float2* tabs  = (float2*)d_ws;
    float2* T1    = (float2*)((char*)d_ws + 32768);
    uint4*  Ftab  = (uint4*)((char*)d_ws + 49152);
    float2* kf_cd = (float2*)((char*)d_ws + 65536);

    fft_tables<<<16, 256, 0, stream>>>(tabs, T1, Ftab);
    kf_kernel<<<128, 256, 0, stream>>>(k, tabs, kf_cd);
    conv_mfma<<<1024, 256, 0, stream>>>(u, T1, Ftab, kf_cd, out);
}

// Round 12
// 48.012 us; speedup vs baseline: 1.3289x; 1.3289x over previous
//
#include <hip/hip_runtime.h>
#include <hip/hip_bf16.h>
#include <math.h>

typedef __attribute__((ext_vector_type(8))) short short8;
typedef __attribute__((ext_vector_type(16))) float f32x16;

union U {
    unsigned u[4];
    short8 s;
};

struct FragH {         // one component (re or im) bf16 operand, 2 k-tiles
    U f[2];
};

static __device__ __forceinline__ unsigned short f2bf(float x) {
    __bf16 b = (__bf16)x;                       // RNE, native v_cvt on gfx950
    return __builtin_bit_cast(unsigned short, b);
}
static __device__ __forceinline__ unsigned packbf(float a, float b) {
    return (unsigned)f2bf(a) | ((unsigned)f2bf(b) << 16);
}

#define MFMA(A, B, C) __builtin_amdgcn_mfma_f32_32x32x16_bf16((A).s, (B).s, (C), 0, 0, 0)

// ---------------------------------------------------------------------------
// Workspace layout (bytes):
//   0      : tabs  float2[4096]  (F, Finv, -, conj-twiddle -- for kf_kernel)
//   49152  : Ftab  uint4 [384]   (bf16 fragment tables: cos, -sin, +sin)
//   65536  : kf_cd float2[128*1024] (filter spectrum / 1024, C/D order)
// ---------------------------------------------------------------------------

__global__ __launch_bounds__(256) void fft_tables(float2* tabs, uint4* Ftab) {
    int gid = blockIdx.x * 256 + threadIdx.x;       // grid 16*256 = 4096
    if (gid < 1024) {
        int i = gid;
        int r = i >> 5, c = i & 31;
        float s32, c32;
        sincospif((float)((r * c) & 31) / 16.0f, &s32, &c32);
        s32 = -s32;                                  // exp(-2pi i rc/32)
        tabs[i]        = make_float2(c32,  s32);     // F
        tabs[1024 + i] = make_float2(c32, -s32);     // Finv
        float sN, cN;
        sincospif((float)(r * c) / 512.0f, &sN, &cN);
        sN = -sN;                                    // exp(-2pi i rc/1024)
        tabs[2048 + i] = make_float2(cN / 1024.0f, sN / 1024.0f);
        tabs[3072 + i] = make_float2(cN, -sN);
    }
    if (gid < 1536) {
        // Ftab: 3 comps x 2 ktiles x 64 lanes x 4 vgprs, packed bf16 pairs.
        // comp 0: cos ; 1: -sin (=im F) ; 2: +sin (=im Finv)
        int c = gid >> 9;
        int rem = gid & 511;
        int t = rem >> 8;
        int sub = rem & 255;
        int l = sub >> 2;
        int v = sub & 3;
        int k0 = 16 * t + 8 * (l >> 5) + 2 * v;
        int j = l & 31;
        unsigned short sh[2];
        for (int q = 0; q < 2; q++) {
            int k = k0 + q;
            float sa, ca;
            sincospif((float)((k * j) & 31) / 16.0f, &sa, &ca);
            float base = (c == 0) ? ca : ((c == 1) ? -sa : sa);
            sh[q] = f2bf(base);
        }
        ((unsigned*)Ftab)[((c * 2 + t) * 64 + l) * 4 + v] =
            (unsigned)sh[0] | ((unsigned)sh[1] << 16);
    }
}

// Filter spectrum kfT[h][k1][k2] = FFT_1024(k[h])[32*k2+k1], written permuted
// AND scaled by 1/1024: kf_cd[h][m][l] = kfT[h][l&31][row(m,l)] / 1024
__global__ __launch_bounds__(256) void kf_kernel(const float* __restrict__ kin,
                                                 const float2* __restrict__ tabs,
                                                 float2* __restrict__ kf_cd) {
    __shared__ float  sx[1024];
    __shared__ float2 sA[1024];
    const int h = blockIdx.x, t = threadIdx.x;
    for (int i = t; i < 1024; i += 256) sx[i] = kin[h * 1024 + i];
    __syncthreads();
    const int r = t >> 3, c0 = (t & 7) << 2;

    float2 acc[4];
    for (int j = 0; j < 4; j++) acc[j] = make_float2(0.f, 0.f);
    #pragma unroll 8
    for (int n1 = 0; n1 < 32; n1++) {
        float2 f = tabs[r * 32 + n1];
        for (int j = 0; j < 4; j++) {
            float xv = sx[n1 * 32 + c0 + j];
            acc[j].x += f.x * xv;
            acc[j].y += f.y * xv;
        }
    }
    for (int j = 0; j < 4; j++) {
        float2 w = tabs[3072 + r * 32 + c0 + j];   // conj -> exp(-2pi i rc/N)
        sA[r * 32 + c0 + j] = make_float2(acc[j].x * w.x + acc[j].y * w.y,
                                          acc[j].y * w.x - acc[j].x * w.y);
    }
    __syncthreads();
    for (int j = 0; j < 4; j++) acc[j] = make_float2(0.f, 0.f);
    #pragma unroll 8
    for (int n2 = 0; n2 < 32; n2++) {
        float2 a = sA[r * 32 + n2];
        for (int j = 0; j < 4; j++) {
            float2 f = tabs[n2 * 32 + c0 + j];
            acc[j].x += a.x * f.x - a.y * f.y;
            acc[j].y += a.x * f.y + a.y * f.x;
        }
    }
    for (int j = 0; j < 4; j++) {
        int k2 = c0 + j;
        int m = (k2 & 3) | ((k2 >> 3) << 2);
        int hl = (k2 >> 2) & 1;
        kf_cd[h * 1024 + m * 64 + hl * 32 + r] =
            make_float2(acc[j].x * (1.0f / 1024.0f), acc[j].y * (1.0f / 1024.0f));
    }
}

// C/D accumulator -> bf16 A/B fragment via v_permlane32_swap_b32:
// swap(a,b): a.hi <-> b.lo => a = [a.lo;b.lo], b = [a.hi;b.hi]
static __device__ __forceinline__ void convertP(const f32x16& acc, FragH& out) {
    #pragma unroll
    for (int t = 0; t < 2; t++) {
        unsigned a0 = packbf(acc[8 * t + 0], acc[8 * t + 1]);
        unsigned a1 = packbf(acc[8 * t + 2], acc[8 * t + 3]);
        unsigned b0 = packbf(acc[8 * t + 4], acc[8 * t + 5]);
        unsigned b1 = packbf(acc[8 * t + 6], acc[8 * t + 7]);
        asm("v_permlane32_swap_b32 %0, %1" : "+v"(a0), "+v"(b0));
        asm("v_permlane32_swap_b32 %0, %1" : "+v"(a1), "+v"(b1));
        out.f[t].u[0] = a0;
        out.f[t].u[1] = a1;
        out.f[t].u[2] = b0;
        out.f[t].u[3] = b1;
    }
}

// R12: R8 structure (1 packed pair/wave, grid 2048x4 waves) slimmed to fit
// 4 waves/SIMD (<=128 unified regs):
//  - F operand tables in LDS (read per k-tile inside the MFMA clusters);
//  - twiddles recomputed inline via v_cos/v_sin (revolutions), zero residency;
//  - (256,4). Tripwire: WRITE_SIZE must stay 65536 KB, else this spilled.
__global__ __launch_bounds__(256, 4) void conv_mfma(const float* __restrict__ u,
                                                    const uint4* __restrict__ Ftab,
                                                    const float2* __restrict__ KF,
                                                    float* __restrict__ out) {
    __shared__ uint4  sF[384];      // 6 KB: F fragments (cos, -sin, +sin) x 2 kt
    __shared__ float2 sKF[1024];    // 8 KB: this block's h filter spectrum

    const int tid = threadIdx.x;
    const int lane = tid & 63;
    const int wave = tid >> 6;
    const int col = lane & 31;
    const int hl = lane >> 5;
    const size_t tile_stride = (size_t)128 * 1024;

    const int pair = blockIdx.x * 4 + wave;   // 0..8191
    const int h = blockIdx.x >> 4;            // uniform per block
    const int b0 = (pair & 63) * 2;

    for (int i = tid; i < 384; i += 256) sF[i] = Ftab[i];
    for (int i = tid; i < 1024; i += 256) sKF[i] = KF[h * 1024 + i];
    __syncthreads();

    const f32x16 Z16 = {0,0,0,0,0,0,0,0,0,0,0,0,0,0,0,0};

    // ---- Input: Xr = u[b0] tile, Xi = u[b0+1] tile (transposed read),
    // packed to bf16 immediately.
    const float* upr = u + ((size_t)(b0 * 128 + h) << 10);
    const float* upi = upr + tile_stride;
    U Xr[2], Xi[2];
    #pragma unroll
    for (int t = 0; t < 2; t++) {
        #pragma unroll
        for (int v = 0; v < 4; v++) {
            int off = (16 * t + 8 * hl + 2 * v) * 32 + col;
            Xr[t].u[v] = packbf(upr[off], upr[off + 32]);
            Xi[t].u[v] = packbf(upi[off], upi[off + 32]);
        }
    }

    // F operand loader (LDS -> 4 VGPRs, transient).
    #define LOADF(c, t) ({ U r_; uint4 raw_ = sF[((c) * 2 + (t)) * 64 + lane]; \
        r_.u[0] = raw_.x; r_.u[1] = raw_.y; r_.u[2] = raw_.z; r_.u[3] = raw_.w; r_; })

    // ---- Stage 1: Y^T = Z^T @ F   (Yr = Xr@C + Xi@sin ; Yi = Xr@S + Xi@C)
    f32x16 aR = Z16, aI = Z16;
    #pragma unroll
    for (int t = 0; t < 2; t++) {
        U F0 = LOADF(0, t), F1 = LOADF(1, t), F2 = LOADF(2, t);
        aR = MFMA(Xr[t], F0, aR); aR = MFMA(Xi[t], F2, aR);
        aI = MFMA(Xr[t], F1, aI); aI = MFMA(Xi[t], F0, aI);
    }
    #pragma unroll
    for (int m = 0; m < 16; m++) {                 // twiddle, inline trig
        int row = (m & 3) + 8 * (m >> 2) + 4 * hl;
        float rev = (float)(col * row) * (1.0f / 1024.0f);
        float cc = __builtin_amdgcn_cosf(rev), ss = __builtin_amdgcn_sinf(rev);
        float rr = aR[m] * cc + aI[m] * ss;
        float ii = aI[m] * cc - aR[m] * ss;
        aR[m] = rr; aI[m] = ii;
    }
    FragH Yr, Yi;
    convertP(aR, Yr);
    convertP(aI, Yi);

    // ---- Stage 3: Z^T = F @ Y^T  (Zr = C@Yr + sin@Yi ; Zi = C@Yi + S@Yr)
    f32x16 bR = Z16, bI = Z16;
    #pragma unroll
    for (int t = 0; t < 2; t++) {
        U F0 = LOADF(0, t), F1 = LOADF(1, t), F2 = LOADF(2, t);
        bR = MFMA(F0, Yr.f[t], bR); bR = MFMA(F2, Yi.f[t], bR);
        bI = MFMA(F0, Yi.f[t], bI); bI = MFMA(F1, Yr.f[t], bI);
    }
    #pragma unroll
    for (int m = 0; m < 16; m++) {                 // filter (has 1/N)
        float2 kv = sKF[m * 64 + lane];
        float rr = bR[m] * kv.x - bI[m] * kv.y;
        float ii = bR[m] * kv.y + bI[m] * kv.x;
        bR[m] = rr; bI[m] = ii;
    }
    FragH Zr, Zi;
    convertP(bR, Zr);
    convertP(bI, Zi);

    // ---- Stage 5: W = Z @ Finv  (Wr = Zr@C + Zi@S ; Wi = Zr@sin + Zi@C)
    aR = Z16; aI = Z16;
    #pragma unroll
    for (int t = 0; t < 2; t++) {
        U F0 = LOADF(0, t), F1 = LOADF(1, t), F2 = LOADF(2, t);
        aR = MFMA(Zr.f[t], F0, aR); aR = MFMA(Zi.f[t], F1, aR);
        aI = MFMA(Zr.f[t], F2, aI); aI = MFMA(Zi.f[t], F0, aI);
    }
    #pragma unroll
    for (int m = 0; m < 16; m++) {                 // conj twiddle, inline trig
        int row = (m & 3) + 8 * (m >> 2) + 4 * hl;
        float rev = (float)(col * row) * (1.0f / 1024.0f);
        float cc = __builtin_amdgcn_cosf(rev), ss = __builtin_amdgcn_sinf(rev);
        float rr = aR[m] * cc - aI[m] * ss;
        float ii = aI[m] * cc + aR[m] * ss;
        aR[m] = rr; aI[m] = ii;
    }
    FragH Wr, Wi;
    convertP(aR, Wr);
    convertP(aI, Wi);

    // ---- Stage 7: y = Finv @ W  (yR = C@Wr + S@Wi ; yI = C@Wi + sin@Wr)
    f32x16 yR = Z16, yI = Z16;
    #pragma unroll
    for (int t = 0; t < 2; t++) {
        U F0 = LOADF(0, t), F1 = LOADF(1, t), F2 = LOADF(2, t);
        yR = MFMA(F0, Wr.f[t], yR); yR = MFMA(F1, Wi.f[t], yR);
        yI = MFMA(F0, Wi.f[t], yI); yI = MFMA(F2, Wr.f[t], yI);
    }
    float* opr = out + ((size_t)(b0 * 128 + h) << 10);
    float* opi = opr + tile_stride;
    #pragma unroll
    for (int m = 0; m < 16; m++) {
        int off = ((m & 3) + 8 * (m >> 2) + 4 * hl) * 32 + col;
        opr[off] = yR[m];
        opi[off] = yI[m];
    }
    #undef LOADF
}

extern "C" void kernel_launch(void* const* d_in, const int* in_sizes, int n_in,
                              void* d_out, int out_size, void* d_ws, size_t ws_size,
                              hipStream_t stream) {
    const float* u = (const float*)d_in[0];   // (B=128, H=128, N=1024)
    const float* k = (const float*)d_in[1];   // (H=128, N=1024)
    float* out = (float*)d_out;               // (B, H, N) float32

    float2* tabs  = (float2*)d_ws;
    uint4*  Ftab  = (uint4*)((char*)d_ws + 49152);
    float2* kf_cd = (float2*)((char*)d_ws + 65536);

    fft_tables<<<16, 256, 0, stream>>>(tabs, Ftab);
    kf_kernel<<<128, 256, 0, stream>>>(k, tabs, kf_cd);
    conv_mfma<<<2048, 256, 0, stream>>>(u, Ftab, kf_cd, out);
}

// Round 13
// 46.115 us; speedup vs baseline: 1.3836x; 1.0411x over previous
//
#include <hip/hip_runtime.h>
#include <hip/hip_bf16.h>
#include <math.h>

typedef __attribute__((ext_vector_type(8))) short short8;
typedef __attribute__((ext_vector_type(16))) float f32x16;

union U {
    unsigned u[4];
    short8 s;
};

struct FragH {         // one component (re or im) bf16 operand, 2 k-tiles
    U f[2];
};

static __device__ __forceinline__ unsigned short f2bf(float x) {
    __bf16 b = (__bf16)x;                       // RNE, native v_cvt on gfx950
    return __builtin_bit_cast(unsigned short, b);
}
static __device__ __forceinline__ unsigned packbf(float a, float b) {
    return (unsigned)f2bf(a) | ((unsigned)f2bf(b) << 16);
}

#define MFMA(A, B, C) __builtin_amdgcn_mfma_f32_32x32x16_bf16((A).s, (B).s, (C), 0, 0, 0)

// ---------------------------------------------------------------------------
// Workspace layout (bytes):
//   0      : tabs  float2[4096]  (F, Finv, -, conj-twiddle -- for kf_kernel)
//   32768  : T1    float2[1024]  (pure twiddle exp(-2pi i rc/N), C/D order)
//   49152  : Ftab  uint4 [384]   (bf16 fragment tables: cos, -sin, +sin)
//   65536  : kf_cd float2[128*1024] (filter spectrum / 1024, C/D order)
// ---------------------------------------------------------------------------

__global__ __launch_bounds__(256) void fft_tables(float2* tabs, float2* T1, uint4* Ftab) {
    int gid = blockIdx.x * 256 + threadIdx.x;       // grid 16*256 = 4096
    if (gid < 1024) {
        int i = gid;
        int r = i >> 5, c = i & 31;
        float s32, c32;
        sincospif((float)((r * c) & 31) / 16.0f, &s32, &c32);
        s32 = -s32;                                  // exp(-2pi i rc/32)
        tabs[i]        = make_float2(c32,  s32);     // F
        tabs[1024 + i] = make_float2(c32, -s32);     // Finv
        float sN, cN;
        sincospif((float)(r * c) / 512.0f, &sN, &cN);
        sN = -sN;                                    // exp(-2pi i rc/1024)
        tabs[2048 + i] = make_float2(cN / 1024.0f, sN / 1024.0f);
        tabs[3072 + i] = make_float2(cN, -sN);
        // T1[m][l] = twiddle[l&31][row(m,l)] (symmetric), no 1/N (in kf_cd)
        int m = i >> 6, l = i & 63;
        int row = (m & 3) + 8 * (m >> 2) + 4 * (l >> 5);
        int prod = (l & 31) * row;
        float st, ct;
        sincospif((float)prod / 512.0f, &st, &ct);
        T1[i] = make_float2(ct, -st);
    }
    if (gid < 1536) {
        // Ftab: 3 comps x 2 ktiles x 64 lanes x 4 vgprs, packed bf16 pairs.
        // comp 0: cos ; 1: -sin (=im F) ; 2: +sin (=im Finv)
        int c = gid >> 9;
        int rem = gid & 511;
        int t = rem >> 8;
        int sub = rem & 255;
        int l = sub >> 2;
        int v = sub & 3;
        int k0 = 16 * t + 8 * (l >> 5) + 2 * v;
        int j = l & 31;
        unsigned short sh[2];
        for (int q = 0; q < 2; q++) {
            int k = k0 + q;
            float sa, ca;
            sincospif((float)((k * j) & 31) / 16.0f, &sa, &ca);
            float base = (c == 0) ? ca : ((c == 1) ? -sa : sa);
            sh[q] = f2bf(base);
        }
        ((unsigned*)Ftab)[((c * 2 + t) * 64 + l) * 4 + v] =
            (unsigned)sh[0] | ((unsigned)sh[1] << 16);
    }
}

// Filter spectrum kfT[h][k1][k2] = FFT_1024(k[h])[32*k2+k1], written permuted
// AND scaled by 1/1024: kf_cd[h][m][l] = kfT[h][l&31][row(m,l)] / 1024
__global__ __launch_bounds__(256) void kf_kernel(const float* __restrict__ kin,
                                                 const float2* __restrict__ tabs,
                                                 float2* __restrict__ kf_cd) {
    __shared__ float  sx[1024];
    __shared__ float2 sA[1024];
    const int h = blockIdx.x, t = threadIdx.x;
    for (int i = t; i < 1024; i += 256) sx[i] = kin[h * 1024 + i];
    __syncthreads();
    const int r = t >> 3, c0 = (t & 7) << 2;

    float2 acc[4];
    for (int j = 0; j < 4; j++) acc[j] = make_float2(0.f, 0.f);
    #pragma unroll 8
    for (int n1 = 0; n1 < 32; n1++) {
        float2 f = tabs[r * 32 + n1];
        for (int j = 0; j < 4; j++) {
            float xv = sx[n1 * 32 + c0 + j];
            acc[j].x += f.x * xv;
            acc[j].y += f.y * xv;
        }
    }
    for (int j = 0; j < 4; j++) {
        float2 w = tabs[3072 + r * 32 + c0 + j];   // conj -> exp(-2pi i rc/N)
        sA[r * 32 + c0 + j] = make_float2(acc[j].x * w.x + acc[j].y * w.y,
                                          acc[j].y * w.x - acc[j].x * w.y);
    }
    __syncthreads();
    for (int j = 0; j < 4; j++) acc[j] = make_float2(0.f, 0.f);
    #pragma unroll 8
    for (int n2 = 0; n2 < 32; n2++) {
        float2 a = sA[r * 32 + n2];
        for (int j = 0; j < 4; j++) {
            float2 f = tabs[n2 * 32 + c0 + j];
            acc[j].x += a.x * f.x - a.y * f.y;
            acc[j].y += a.x * f.y + a.y * f.x;
        }
    }
    for (int j = 0; j < 4; j++) {
        int k2 = c0 + j;
        int m = (k2 & 3) | ((k2 >> 3) << 2);
        int hl = (k2 >> 2) & 1;
        kf_cd[h * 1024 + m * 64 + hl * 32 + r] =
            make_float2(acc[j].x * (1.0f / 1024.0f), acc[j].y * (1.0f / 1024.0f));
    }
}

// C/D accumulator -> bf16 A/B fragment via v_permlane32_swap_b32:
// swap(a,b): a.hi <-> b.lo => a = [a.lo;b.lo], b = [a.hi;b.hi]
static __device__ __forceinline__ void convertP(const f32x16& acc, FragH& out) {
    #pragma unroll
    for (int t = 0; t < 2; t++) {
        unsigned a0 = packbf(acc[8 * t + 0], acc[8 * t + 1]);
        unsigned a1 = packbf(acc[8 * t + 2], acc[8 * t + 3]);
        unsigned b0 = packbf(acc[8 * t + 4], acc[8 * t + 5]);
        unsigned b1 = packbf(acc[8 * t + 6], acc[8 * t + 7]);
        asm("v_permlane32_swap_b32 %0, %1" : "+v"(a0), "+v"(b0));
        asm("v_permlane32_swap_b32 %0, %1" : "+v"(a1), "+v"(b1));
        out.f[t].u[0] = a0;
        out.f[t].u[1] = a1;
        out.f[t].u[2] = b0;
        out.f[t].u[3] = b1;
    }
}

// R13: R8 compute pipeline, but ALL HBM traffic float4-shaped via LDS staging.
// Block = 4 waves = 4 packed pairs = 8 b-tiles (32 KB in / 32 KB out), one h.
// HBM pattern theory: R7-R12 all plateau at ~2.4 TB/s effective with dword
// access; float4 streaming (m13 pattern) reaches 6.3.
__global__ __launch_bounds__(256, 3) void conv_mfma(const float* __restrict__ u,
                                                    const float2* __restrict__ T1,
                                                    const uint4* __restrict__ Ftab,
                                                    const float2* __restrict__ KF,
                                                    float* __restrict__ out) {
    __shared__ float  sIO[8 * 1024];   // 32 KB: 8 tiles, in then out (reused)
    __shared__ float2 sT1[1024];       // 8 KB
    __shared__ float2 sKF[1024];       // 8 KB

    const int tid = threadIdx.x;
    const int lane = tid & 63;
    const int wave = tid >> 6;
    const int col = lane & 31;
    const int hl = lane >> 5;

    const int h = blockIdx.x >> 4;            // 16 blocks per h
    const int bblk = (blockIdx.x & 15) * 8;   // tiles bblk..bblk+7

    // ---- Stage 8 input tiles to LDS with pure float4 streaming loads.
    #pragma unroll
    for (int j = 0; j < 8; j++) {
        const float4* src = (const float4*)(u + ((size_t)((bblk + j) * 128 + h) << 10));
        *(float4*)&sIO[j * 1024 + tid * 4] = src[tid];
    }
    // ---- Stage tables.
    for (int i = tid; i < 1024; i += 256) {
        sT1[i] = T1[i];
        sKF[i] = KF[h * 1024 + i];
    }

    // ---- F fragment tables (regs): F[0]=cos, F[1]=-sin, F[2]=+sin
    U F[3][2];
    #pragma unroll
    for (int c = 0; c < 3; c++)
        #pragma unroll
        for (int t = 0; t < 2; t++) {
            uint4 raw = Ftab[(c * 2 + t) * 64 + lane];
            F[c][t].u[0] = raw.x; F[c][t].u[1] = raw.y;
            F[c][t].u[2] = raw.z; F[c][t].u[3] = raw.w;
        }
    __syncthreads();

    // ---- Read this wave's fragments from LDS (bank = col: conflict-free).
    // Wave w: tile 2w = Re part (b = bblk+2w), tile 2w+1 = Im part.
    const int tR = wave * 2, tI = wave * 2 + 1;
    U Xr[2], Xi[2];
    #pragma unroll
    for (int t = 0; t < 2; t++)
        #pragma unroll
        for (int v = 0; v < 4; v++) {
            int r0 = (16 * t + 8 * hl + 2 * v) * 32 + col;
            Xr[t].u[v] = packbf(sIO[tR * 1024 + r0], sIO[tR * 1024 + r0 + 32]);
            Xi[t].u[v] = packbf(sIO[tI * 1024 + r0], sIO[tI * 1024 + r0 + 32]);
        }

    const f32x16 Z16 = {0,0,0,0,0,0,0,0,0,0,0,0,0,0,0,0};

    // ---- Stage 1: Y^T = Z^T @ F   (Yr = Xr@C + Xi@sin ; Yi = Xr@S + Xi@C)
    f32x16 aR = Z16, aI = Z16;
    #pragma unroll
    for (int t = 0; t < 2; t++) {
        aR = MFMA(Xr[t], F[0][t], aR); aR = MFMA(Xi[t], F[2][t], aR);
        aI = MFMA(Xr[t], F[1][t], aI); aI = MFMA(Xi[t], F[0][t], aI);
    }
    #pragma unroll
    for (int m = 0; m < 16; m++) {                 // twiddle (1/N in kf)
        float2 tm = sT1[m * 64 + lane];
        float rr = aR[m] * tm.x - aI[m] * tm.y;
        float ii = aR[m] * tm.y + aI[m] * tm.x;
        aR[m] = rr; aI[m] = ii;
    }
    FragH Yr, Yi;
    convertP(aR, Yr);
    convertP(aI, Yi);

    // ---- Stage 3: Z^T = F @ Y^T  (Zr = C@Yr + sin@Yi ; Zi = C@Yi + S@Yr)
    f32x16 bR = Z16, bI = Z16;
    #pragma unroll
    for (int t = 0; t < 2; t++) {
        bR = MFMA(F[0][t], Yr.f[t], bR); bR = MFMA(F[2][t], Yi.f[t], bR);
        bI = MFMA(F[0][t], Yi.f[t], bI); bI = MFMA(F[1][t], Yr.f[t], bI);
    }
    #pragma unroll
    for (int m = 0; m < 16; m++) {                 // filter (has 1/N)
        float2 kv = sKF[m * 64 + lane];
        float rr = bR[m] * kv.x - bI[m] * kv.y;
        float ii = bR[m] * kv.y + bI[m] * kv.x;
        bR[m] = rr; bI[m] = ii;
    }
    FragH Zr, Zi;
    convertP(bR, Zr);
    convertP(bI, Zi);

    // ---- Stage 5: W = Z @ Finv  (Wr = Zr@C + Zi@S ; Wi = Zr@sin + Zi@C)
    aR = Z16; aI = Z16;
    #pragma unroll
    for (int t = 0; t < 2; t++) {
        aR = MFMA(Zr.f[t], F[0][t], aR); aR = MFMA(Zi.f[t], F[1][t], aR);
        aI = MFMA(Zr.f[t], F[2][t], aI); aI = MFMA(Zi.f[t], F[0][t], aI);
    }
    #pragma unroll
    for (int m = 0; m < 16; m++) {                 // conj twiddle (no scale)
        float2 tm = sT1[m * 64 + lane];
        float rr = aR[m] * tm.x + aI[m] * tm.y;
        float ii = aI[m] * tm.x - aR[m] * tm.y;
        aR[m] = rr; aI[m] = ii;
    }
    FragH Wr, Wi;
    convertP(aR, Wr);
    convertP(aI, Wi);

    // ---- Stage 7: y = Finv @ W  (yR = C@Wr + S@Wi ; yI = C@Wi + sin@Wr)
    f32x16 yR = Z16, yI = Z16;
    #pragma unroll
    for (int t = 0; t < 2; t++) {
        yR = MFMA(F[0][t], Wr.f[t], yR); yR = MFMA(F[1][t], Wi.f[t], yR);
        yI = MFMA(F[0][t], Wi.f[t], yI); yI = MFMA(F[2][t], Wr.f[t], yI);
    }

    // ---- Write outputs back into sIO (same-wave tiles: ds ordering safe).
    #pragma unroll
    for (int m = 0; m < 16; m++) {
        int off = ((m & 3) + 8 * (m >> 2) + 4 * hl) * 32 + col;
        sIO[tR * 1024 + off] = yR[m];
        sIO[tI * 1024 + off] = yI[m];
    }
    __syncthreads();

    // ---- Stream 8 output tiles to global with pure float4 stores.
    #pragma unroll
    for (int j = 0; j < 8; j++) {
        float4* dst = (float4*)(out + ((size_t)((bblk + j) * 128 + h) << 10));
        dst[tid] = *(const float4*)&sIO[j * 1024 + tid * 4];
    }
}

extern "C" void kernel_launch(void* const* d_in, const int* in_sizes, int n_in,
                              void* d_out, int out_size, void* d_ws, size_t ws_size,
                              hipStream_t stream) {
    const float* u = (const float*)d_in[0];   // (B=128, H=128, N=1024)
    const float* k = (const float*)d_in[1];   // (H=128, N=1024)
    float* out = (float*)d_out;               // (B, H, N) float32

    float2* tabs  = (float2*)d_ws;
    float2* T1    = (float2*)((char*)d_ws + 32768);
    uint4*  Ftab  = (uint4*)((char*)d_ws + 49152);
    float2* kf_cd = (float2*)((char*)d_ws + 65536);

    fft_tables<<<16, 256, 0, stream>>>(tabs, T1, Ftab);
    kf_kernel<<<128, 256, 0, stream>>>(k, tabs, kf_cd);
    conv_mfma<<<2048, 256, 0, stream>>>(u, T1, Ftab, kf_cd, out);
}

// Round 14
// 43.747 us; speedup vs baseline: 1.4585x; 1.0541x over previous
//
#include <hip/hip_runtime.h>
#include <hip/hip_bf16.h>
#include <math.h>

typedef __attribute__((ext_vector_type(8))) short short8;
typedef __attribute__((ext_vector_type(16))) float f32x16;

union U {
    unsigned u[4];
    short8 s;
};

struct FragH {         // one component (re or im) bf16 operand, 2 k-tiles
    U f[2];
};

static __device__ __forceinline__ unsigned short f2bf(float x) {
    __bf16 b = (__bf16)x;                       // RNE, native v_cvt on gfx950
    return __builtin_bit_cast(unsigned short, b);
}
static __device__ __forceinline__ unsigned packbf(float a, float b) {
    return (unsigned)f2bf(a) | ((unsigned)f2bf(b) << 16);
}

#define MFMA(A, B, C) __builtin_amdgcn_mfma_f32_32x32x16_bf16((A).s, (B).s, (C), 0, 0, 0)

// Async global->LDS, 16 B/lane, LDS dest = wave-uniform base + lane*16.
static __device__ __forceinline__ void gll16(const float* g, float* l) {
    __builtin_amdgcn_global_load_lds(
        (const __attribute__((address_space(1))) void*)g,
        (__attribute__((address_space(3))) void*)l, 16, 0, 0);
}

// ---------------------------------------------------------------------------
// Workspace layout (bytes):
//   0      : tabs  float2[4096]  (F, Finv, -, conj-twiddle -- for kf_kernel)
//   49152  : Ftab  uint4 [384]   (bf16 fragment tables: cos, -sin, +sin)
//   65536  : kf_cd float2[128*1024] (filter spectrum / 1024, C/D order)
// ---------------------------------------------------------------------------

__global__ __launch_bounds__(256) void fft_tables(float2* tabs, uint4* Ftab) {
    int gid = blockIdx.x * 256 + threadIdx.x;       // grid 16*256 = 4096
    if (gid < 1024) {
        int i = gid;
        int r = i >> 5, c = i & 31;
        float s32, c32;
        sincospif((float)((r * c) & 31) / 16.0f, &s32, &c32);
        s32 = -s32;                                  // exp(-2pi i rc/32)
        tabs[i]        = make_float2(c32,  s32);     // F
        tabs[1024 + i] = make_float2(c32, -s32);     // Finv
        float sN, cN;
        sincospif((float)(r * c) / 512.0f, &sN, &cN);
        sN = -sN;                                    // exp(-2pi i rc/1024)
        tabs[2048 + i] = make_float2(cN / 1024.0f, sN / 1024.0f);
        tabs[3072 + i] = make_float2(cN, -sN);
    }
    if (gid < 1536) {
        // Ftab: comp 0: cos ; 1: -sin ; 2: +sin
        int c = gid >> 9;
        int rem = gid & 511;
        int t = rem >> 8;
        int sub = rem & 255;
        int l = sub >> 2;
        int v = sub & 3;
        int k0 = 16 * t + 8 * (l >> 5) + 2 * v;
        int j = l & 31;
        unsigned short sh[2];
        for (int q = 0; q < 2; q++) {
            int k = k0 + q;
            float sa, ca;
            sincospif((float)((k * j) & 31) / 16.0f, &sa, &ca);
            float base = (c == 0) ? ca : ((c == 1) ? -sa : sa);
            sh[q] = f2bf(base);
        }
        ((unsigned*)Ftab)[((c * 2 + t) * 64 + l) * 4 + v] =
            (unsigned)sh[0] | ((unsigned)sh[1] << 16);
    }
}

__global__ __launch_bounds__(256) void kf_kernel(const float* __restrict__ kin,
                                                 const float2* __restrict__ tabs,
                                                 float2* __restrict__ kf_cd) {
    __shared__ float  sx[1024];
    __shared__ float2 sA[1024];
    const int h = blockIdx.x, t = threadIdx.x;
    for (int i = t; i < 1024; i += 256) sx[i] = kin[h * 1024 + i];
    __syncthreads();
    const int r = t >> 3, c0 = (t & 7) << 2;

    float2 acc[4];
    for (int j = 0; j < 4; j++) acc[j] = make_float2(0.f, 0.f);
    #pragma unroll 8
    for (int n1 = 0; n1 < 32; n1++) {
        float2 f = tabs[r * 32 + n1];
        for (int j = 0; j < 4; j++) {
            float xv = sx[n1 * 32 + c0 + j];
            acc[j].x += f.x * xv;
            acc[j].y += f.y * xv;
        }
    }
    for (int j = 0; j < 4; j++) {
        float2 w = tabs[3072 + r * 32 + c0 + j];   // conj -> exp(-2pi i rc/N)
        sA[r * 32 + c0 + j] = make_float2(acc[j].x * w.x + acc[j].y * w.y,
                                          acc[j].y * w.x - acc[j].x * w.y);
    }
    __syncthreads();
    for (int j = 0; j < 4; j++) acc[j] = make_float2(0.f, 0.f);
    #pragma unroll 8
    for (int n2 = 0; n2 < 32; n2++) {
        float2 a = sA[r * 32 + n2];
        for (int j = 0; j < 4; j++) {
            float2 f = tabs[n2 * 32 + c0 + j];
            acc[j].x += a.x * f.x - a.y * f.y;
            acc[j].y += a.x * f.y + a.y * f.x;
        }
    }
    for (int j = 0; j < 4; j++) {
        int k2 = c0 + j;
        int m = (k2 & 3) | ((k2 >> 3) << 2);
        int hl = (k2 >> 2) & 1;
        kf_cd[h * 1024 + m * 64 + hl * 32 + r] =
            make_float2(acc[j].x * (1.0f / 1024.0f), acc[j].y * (1.0f / 1024.0f));
    }
}

// C/D accumulator -> bf16 A/B fragment via v_permlane32_swap_b32.
static __device__ __forceinline__ void convertP(const f32x16& acc, FragH& out) {
    #pragma unroll
    for (int t = 0; t < 2; t++) {
        unsigned a0 = packbf(acc[8 * t + 0], acc[8 * t + 1]);
        unsigned a1 = packbf(acc[8 * t + 2], acc[8 * t + 3]);
        unsigned b0 = packbf(acc[8 * t + 4], acc[8 * t + 5]);
        unsigned b1 = packbf(acc[8 * t + 6], acc[8 * t + 7]);
        asm("v_permlane32_swap_b32 %0, %1" : "+v"(a0), "+v"(b0));
        asm("v_permlane32_swap_b32 %0, %1" : "+v"(a1), "+v"(b1));
        out.f[t].u[0] = a0;
        out.f[t].u[1] = a1;
        out.f[t].u[2] = b0;
        out.f[t].u[3] = b1;
    }
}

// One packed-pair four-step (R8/R10-verified algebra). Tables in registers.
static __device__ __forceinline__ void compute_pair14(
        const U Xr[2], const U Xi[2], const U F[3][2],
        const float2 t1[16], const float2 kf[16],
        float* __restrict__ opr, float* __restrict__ opi,
        int hl, int col) {
    const f32x16 Z16 = {0,0,0,0,0,0,0,0,0,0,0,0,0,0,0,0};

    // Stage 1: Y^T = Z^T @ F
    f32x16 aR = Z16, aI = Z16;
    #pragma unroll
    for (int t = 0; t < 2; t++) {
        aR = MFMA(Xr[t], F[0][t], aR); aR = MFMA(Xi[t], F[2][t], aR);
        aI = MFMA(Xr[t], F[1][t], aI); aI = MFMA(Xi[t], F[0][t], aI);
    }
    #pragma unroll
    for (int m = 0; m < 16; m++) {                 // twiddle (1/N in kf)
        float rr = aR[m] * t1[m].x - aI[m] * t1[m].y;
        float ii = aR[m] * t1[m].y + aI[m] * t1[m].x;
        aR[m] = rr; aI[m] = ii;
    }
    FragH Yr, Yi;
    convertP(aR, Yr);
    convertP(aI, Yi);

    // Stage 3: Z^T = F @ Y^T
    f32x16 bR = Z16, bI = Z16;
    #pragma unroll
    for (int t = 0; t < 2; t++) {
        bR = MFMA(F[0][t], Yr.f[t], bR); bR = MFMA(F[2][t], Yi.f[t], bR);
        bI = MFMA(F[0][t], Yi.f[t], bI); bI = MFMA(F[1][t], Yr.f[t], bI);
    }
    #pragma unroll
    for (int m = 0; m < 16; m++) {                 // filter (has 1/N)
        float rr = bR[m] * kf[m].x - bI[m] * kf[m].y;
        float ii = bR[m] * kf[m].y + bI[m] * kf[m].x;
        bR[m] = rr; bI[m] = ii;
    }
    FragH Zr, Zi;
    convertP(bR, Zr);
    convertP(bI, Zi);

    // Stage 5: W = Z @ Finv
    aR = Z16; aI = Z16;
    #pragma unroll
    for (int t = 0; t < 2; t++) {
        aR = MFMA(Zr.f[t], F[0][t], aR); aR = MFMA(Zi.f[t], F[1][t], aR);
        aI = MFMA(Zr.f[t], F[2][t], aI); aI = MFMA(Zi.f[t], F[0][t], aI);
    }
    #pragma unroll
    for (int m = 0; m < 16; m++) {                 // conj twiddle (no scale)
        float rr = aR[m] * t1[m].x + aI[m] * t1[m].y;
        float ii = aI[m] * t1[m].x - aR[m] * t1[m].y;
        aR[m] = rr; aI[m] = ii;
    }
    FragH Wr, Wi;
    convertP(aR, Wr);
    convertP(aI, Wi);

    // Stage 7: y = Finv @ W
    f32x16 yR = Z16, yI = Z16;
    #pragma unroll
    for (int t = 0; t < 2; t++) {
        yR = MFMA(F[0][t], Wr.f[t], yR); yR = MFMA(F[1][t], Wi.f[t], yR);
        yI = MFMA(F[0][t], Wi.f[t], yI); yI = MFMA(F[2][t], Wr.f[t], yI);
    }
    #pragma unroll
    for (int m = 0; m < 16; m++) {
        int off = ((m & 3) + 8 * (m >> 2) + 4 * hl) * 32 + col;
        opr[off] = yR[m];
        opi[off] = yI[m];
    }
}

// R14: persistent pipeline. 512 blocks (2/CU, ALL resident), 4 waves/block,
// 4 pair-units/wave. Wave-private LDS double buffer, staged via
// global_load_lds (zero VGPR), counted vmcnt (never 0 mid-loop), NO barriers
// anywhere (tables in regs; buffers wave-private).
__global__ __launch_bounds__(256, 2) void conv_mfma(const float* __restrict__ u,
                                                    const uint4* __restrict__ Ftab,
                                                    const float2* __restrict__ KF,
                                                    float* __restrict__ out) {
    __shared__ float sBuf[4][2][2048];   // 64 KB: per-wave double buffers

    const int tid = threadIdx.x;
    const int lane = tid & 63;
    const int wave = tid >> 6;
    const int col = lane & 31;
    const int hl = lane >> 5;
    const size_t tile_stride = (size_t)128 * 1024;

    const int p0 = blockIdx.x * 16 + wave * 4;   // first pair of this wave
    const int h = p0 >> 6;                        // uniform across the 4 units

    // ---- Resident tables (regs): F (24), kf (64), t1 (32).
    U F[3][2];
    #pragma unroll
    for (int c = 0; c < 3; c++)
        #pragma unroll
        for (int t = 0; t < 2; t++) {
            uint4 raw = Ftab[(c * 2 + t) * 64 + lane];
            F[c][t].u[0] = raw.x; F[c][t].u[1] = raw.y;
            F[c][t].u[2] = raw.z; F[c][t].u[3] = raw.w;
        }
    float2 kf[16];
    #pragma unroll
    for (int m = 0; m < 16; m++) kf[m] = KF[h * 1024 + m * 64 + lane];
    float2 t1[16];
    #pragma unroll
    for (int m = 0; m < 16; m++) {
        int row = (m & 3) + 8 * (m >> 2) + 4 * hl;
        float rev = (float)(col * row) * (1.0f / 1024.0f);
        t1[m] = make_float2(__builtin_amdgcn_cosf(rev), -__builtin_amdgcn_sinf(rev));
    }
    // Drain table loads so later counted vmcnt only sees staging ops.
    asm volatile("s_waitcnt vmcnt(0)" ::: "memory");

    float* bufA = &sBuf[wave][0][0];
    float* bufB = &sBuf[wave][1][0];

    // Stage unit j (8 gll ops): Re tile -> buf[0..1024), Im -> buf[1024..2048)
    #define STAGE(j, buf) do {                                                \
        int b0_ = ((p0 + (j)) & 63) * 2;                                      \
        const float* sR_ = u + ((size_t)(b0_ * 128 + h) << 10);               \
        const float* sI_ = sR_ + tile_stride;                                 \
        _Pragma("unroll")                                                     \
        for (int c_ = 0; c_ < 4; c_++) {                                      \
            gll16(sR_ + c_ * 256 + lane * 4, (buf) + c_ * 256);               \
            gll16(sI_ + c_ * 256 + lane * 4, (buf) + 1024 + c_ * 256);        \
        }                                                                     \
    } while (0)

    #define FRAGS(buf, Xr, Xi) do {                                           \
        _Pragma("unroll")                                                     \
        for (int t_ = 0; t_ < 2; t_++)                                        \
            _Pragma("unroll")                                                 \
            for (int v_ = 0; v_ < 4; v_++) {                                  \
                int r0_ = (16 * t_ + 8 * hl + 2 * v_) * 32 + col;             \
                (Xr)[t_].u[v_] = packbf((buf)[r0_], (buf)[r0_ + 32]);         \
                (Xi)[t_].u[v_] = packbf((buf)[1024 + r0_], (buf)[1024 + r0_ + 32]); \
            }                                                                 \
    } while (0)

    #define OUTP(j) (out + ((size_t)((((p0 + (j)) & 63) * 2) * 128 + h) << 10))

    U Xr[2], Xi[2];

    STAGE(0, bufA);
    STAGE(1, bufB);

    // ---- unit 0 (bufA); re-stage A only after its frags are read.
    asm volatile("s_waitcnt vmcnt(8)" ::: "memory");
    FRAGS(bufA, Xr, Xi);
    asm volatile("s_waitcnt lgkmcnt(0)" ::: "memory");
    __builtin_amdgcn_sched_barrier(0);
    STAGE(2, bufA);
    { float* o = OUTP(0); compute_pair14(Xr, Xi, F, t1, kf, o, o + tile_stride, hl, col); }

    // ---- unit 1 (bufB)
    asm volatile("s_waitcnt vmcnt(8)" ::: "memory");
    FRAGS(bufB, Xr, Xi);
    asm volatile("s_waitcnt lgkmcnt(0)" ::: "memory");
    __builtin_amdgcn_sched_barrier(0);
    STAGE(3, bufB);
    { float* o = OUTP(1); compute_pair14(Xr, Xi, F, t1, kf, o, o + tile_stride, hl, col); }

    // ---- unit 2 (bufA)
    asm volatile("s_waitcnt vmcnt(8)" ::: "memory");
    FRAGS(bufA, Xr, Xi);
    { float* o = OUTP(2); compute_pair14(Xr, Xi, F, t1, kf, o, o + tile_stride, hl, col); }

    // ---- unit 3 (bufB)
    asm volatile("s_waitcnt vmcnt(0)" ::: "memory");
    FRAGS(bufB, Xr, Xi);
    { float* o = OUTP(3); compute_pair14(Xr, Xi, F, t1, kf, o, o + tile_stride, hl, col); }

    #undef STAGE
    #undef FRAGS
    #undef OUTP
}

extern "C" void kernel_launch(void* const* d_in, const int* in_sizes, int n_in,
                              void* d_out, int out_size, void* d_ws, size_t ws_size,
                              hipStream_t stream) {
    const float* u = (const float*)d_in[0];   // (B=128, H=128, N=1024)
    const float* k = (const float*)d_in[1];   // (H=128, N=1024)
    float* out = (float*)d_out;               // (B, H, N) float32

    float2* tabs  = (float2*)d_ws;
    uint4*  Ftab  = (uint4*)((char*)d_ws + 49152);
    float2* kf_cd = (float2*)((char*)d_ws + 65536);

    fft_tables<<<16, 256, 0, stream>>>(tabs, Ftab);
    kf_kernel<<<128, 256, 0, stream>>>(k, tabs, kf_cd);
    conv_mfma<<<512, 256, 0, stream>>>(u, Ftab, kf_cd, out);
}